// Round 1
// baseline (82.652 us; speedup 1.0000x reference)
//
#include <hip/hip_runtime.h>

#define H 128
#define NPOS 10
#define ROWS 128
#define BLOCK 512

using bf16x8 = __attribute__((ext_vector_type(8))) short;
using f32x4  = __attribute__((ext_vector_type(4))) float;

__device__ __forceinline__ unsigned short f2bf(float f) {
  unsigned u = __float_as_uint(f);
  u += 0x7FFFu + ((u >> 16) & 1u);   // round-to-nearest-even
  return (unsigned short)(u >> 16);
}

__device__ __forceinline__ float sigm(float x) {
  return __builtin_amdgcn_rcpf(1.0f + __builtin_amdgcn_exp2f(-1.44269504f * x));
}
__device__ __forceinline__ float tanh_f(float x) {
  return 2.0f * __builtin_amdgcn_rcpf(1.0f + __builtin_amdgcn_exp2f(-2.88539008f * x)) - 1.0f;
}

// Build W_T[p][j][k] (bf16), j in [0,512): j<128 -> u col j = W_f[p*H+k][j]
//                                          j>=128 -> iou col (j-128) = W_iou[j-128][p*H+k]
__global__ void prep_wt(const float* __restrict__ Wf, const float* __restrict__ Wiou,
                        unsigned short* __restrict__ wt) {
  int id = blockIdx.x * 256 + threadIdx.x;
  if (id >= NPOS * 512 * H) return;
  int k = id & 127;
  int j = (id >> 7) & 511;
  int p = id >> 16;                     // 512*128 = 65536 per pos
  float v = (j < H) ? Wf[(size_t)(p * H + k) * H + j]
                    : Wiou[(size_t)(j - H) * (NPOS * H) + p * H + k];
  wt[id] = f2bf(v);
}

__global__ __launch_bounds__(BLOCK) void tree_lstm_main(
    const float* __restrict__ child_h, const float* __restrict__ child_c,
    const float* __restrict__ e1, const float* __restrict__ e2,
    const float* __restrict__ h_prev, const int* __restrict__ posp,
    const int* __restrict__ depthp, const int* __restrict__ maskp,
    const float* __restrict__ b_f, const float* __restrict__ b_iou,
    const unsigned short* __restrict__ wt, float* __restrict__ out, int N) {

  __shared__ unsigned short hs[ROWS * H];          // 32 KB, XOR-swizzled bf16 h_cat
  __shared__ int cnt[NPOS], offs[NPOS], compact_[ROWS];
  __shared__ int ck_pos[32], ck_start[32], nck;

  const int t = threadIdx.x;
  const int row0 = blockIdx.x * ROWS;

  if (t < NPOS) cnt[t] = 0;
  __syncthreads();

  int myp = 0, myslot = 0;
  if (t < ROWS) {
    myp = posp[row0 + t];
    myslot = atomicAdd(&cnt[myp], 1);
  }

  // ---- stage h_cat = child_h + (depth==1)*e1 + (depth==2)*e2, as bf16 in LDS ----
  // 2048 chunks of 8 elems; 512 threads x 4 iters
  #pragma unroll
  for (int i = 0; i < (ROWS * H / 8) / BLOCK; ++i) {
    int id = i * BLOCK + t;
    int row = id >> 4, c8 = id & 15;
    int g = row0 + row;
    const float4* ph = (const float4*)(child_h + (size_t)g * H + c8 * 8);
    const float4* p1 = (const float4*)(e1 + (size_t)g * H + c8 * 8);
    const float4* p2 = (const float4*)(e2 + (size_t)g * H + c8 * 8);
    int dep = depthp[g];
    float m1 = (dep == 1) ? 1.0f : 0.0f;
    float m2 = (dep == 2) ? 1.0f : 0.0f;
    float4 a0 = ph[0], a1 = ph[1];
    float4 b0 = p1[0], b1 = p1[1];
    float4 c0 = p2[0], c1 = p2[1];
    bf16x8 v;
    v[0] = (short)f2bf(a0.x + m1 * b0.x + m2 * c0.x);
    v[1] = (short)f2bf(a0.y + m1 * b0.y + m2 * c0.y);
    v[2] = (short)f2bf(a0.z + m1 * b0.z + m2 * c0.z);
    v[3] = (short)f2bf(a0.w + m1 * b0.w + m2 * c0.w);
    v[4] = (short)f2bf(a1.x + m1 * b1.x + m2 * c1.x);
    v[5] = (short)f2bf(a1.y + m1 * b1.y + m2 * c1.y);
    v[6] = (short)f2bf(a1.z + m1 * b1.z + m2 * c1.z);
    v[7] = (short)f2bf(a1.w + m1 * b1.w + m2 * c1.w);
    int wb = (row * 256 + c8 * 16) ^ ((row & 7) << 4);
    *(bf16x8*)((char*)hs + wb) = v;
  }
  __syncthreads();

  // ---- bucket prefix + chunk list (serial, tiny) ----
  if (t == 0) {
    int run = 0, nc = 0;
    for (int p = 0; p < NPOS; ++p) {
      offs[p] = run;
      int c = cnt[p];
      for (int s = 0; s < c; s += 16) { ck_pos[nc] = p; ck_start[nc] = run + s; ++nc; }
      run += c;
    }
    nck = nc;
  }
  __syncthreads();
  if (t < ROWS) compact_[offs[myp] + myslot] = t;
  __syncthreads();

  const int nchunks = nck;
  const int wv = t >> 6, l = t & 63;
  const int l15 = l & 15, lhi = l >> 4;
  const int colr = wv * 16 + l15;          // this wave's output column, 0..127
  const size_t NH = (size_t)N * H;
  const float b_i = b_iou[colr], b_o = b_iou[H + colr], b_g = b_iou[2 * H + colr];

  for (int c = 0; c < nchunks; ++c) {
    const int p = ck_pos[c], cs = ck_start[c];
    const int endp = offs[p] + cnt[p];

    // A fragments: row = compact[cs + (l&15)], k = kk*32 + (l>>4)*8 + j
    int ar = cs + l15;
    int arow = (ar < endp) ? compact_[ar] : 0;   // pad rows read row 0 (discarded)
    bf16x8 afr[4];
    #pragma unroll
    for (int kk = 0; kk < 4; ++kk) {
      int rb = (arow * 256 + kk * 64 + lhi * 16) ^ ((arow & 7) << 4);
      afr[kk] = *(const bf16x8*)((const char*)hs + rb);
    }

    f32x4 au = {0.f, 0.f, 0.f, 0.f};
    f32x4 ai = {0.f, 0.f, 0.f, 0.f};
    f32x4 ao = {0.f, 0.f, 0.f, 0.f};
    f32x4 ag = {0.f, 0.f, 0.f, 0.f};

    const unsigned short* wb0 = wt + (size_t)p * 512 * H + (size_t)colr * H;
    const int kof = lhi * 8;
    #pragma unroll
    for (int kk = 0; kk < 4; ++kk) {
      int ko = kk * 32 + kof;
      bf16x8 bu = *(const bf16x8*)(wb0 + ko);              // u cols
      bf16x8 bi = *(const bf16x8*)(wb0 + 128 * H + ko);    // i cols
      bf16x8 bo = *(const bf16x8*)(wb0 + 256 * H + ko);    // o cols
      bf16x8 bg = *(const bf16x8*)(wb0 + 384 * H + ko);    // g cols
      au = __builtin_amdgcn_mfma_f32_16x16x32_bf16(afr[kk], bu, au, 0, 0, 0);
      ai = __builtin_amdgcn_mfma_f32_16x16x32_bf16(afr[kk], bi, ai, 0, 0, 0);
      ao = __builtin_amdgcn_mfma_f32_16x16x32_bf16(afr[kk], bo, ao, 0, 0, 0);
      ag = __builtin_amdgcn_mfma_f32_16x16x32_bf16(afr[kk], bg, ag, 0, 0, 0);
    }

    // epilogue: D row = (l>>4)*4 + q, col = l&15 (verified m89 mapping)
    const float bfv = b_f[p * H + colr];
    #pragma unroll
    for (int q = 0; q < 4; ++q) {
      int rr = cs + lhi * 4 + q;
      if (rr < endp) {
        int g = row0 + compact_[rr];
        size_t gi = (size_t)g * H + colr;
        float u = au[q] + bfv;
        float iv = ai[q] + b_i;
        float ov = ao[q] + b_o;
        float gv = ag[q] + b_g;
        float f = sigm(u);
        float credv = f * child_c[gi];
        float cnew = sigm(iv) * tanh_f(gv) + credv;
        float hnew = sigm(ov) * tanh_f(cnew);
        float m = (float)maskp[g];
        float hv = h_prev[gi] * m + (1.0f - m) * hnew;
        float cv = credv * m + (1.0f - m) * cnew;
        out[gi] = hv;
        out[NH + gi] = cv;
      }
    }
  }
}

extern "C" void kernel_launch(void* const* d_in, const int* in_sizes, int n_in,
                              void* d_out, int out_size, void* d_ws, size_t ws_size,
                              hipStream_t stream) {
  const float* child_h = (const float*)d_in[0];
  const float* child_c = (const float*)d_in[1];
  const float* e1      = (const float*)d_in[2];
  const float* e2      = (const float*)d_in[3];
  const float* h_prev  = (const float*)d_in[4];
  const int*   posp    = (const int*)d_in[5];
  const int*   depthp  = (const int*)d_in[6];
  const int*   maskp   = (const int*)d_in[7];
  const float* W_f     = (const float*)d_in[8];
  const float* b_f     = (const float*)d_in[9];
  const float* W_iou   = (const float*)d_in[10];
  const float* b_iou   = (const float*)d_in[11];
  float* out = (float*)d_out;
  unsigned short* wt = (unsigned short*)d_ws;   // 10*512*128*2 = 1.31 MB
  int N = in_sizes[0] / H;

  hipLaunchKernelGGL(prep_wt, dim3((NPOS * 512 * H + 255) / 256), dim3(256), 0, stream,
                     W_f, W_iou, wt);
  hipLaunchKernelGGL(tree_lstm_main, dim3(N / ROWS), dim3(BLOCK), 0, stream,
                     child_h, child_c, e1, e2, h_prev, posp, depthp, maskp,
                     b_f, b_iou, wt, out, N);
}